// Round 10
// baseline (361.503 us; speedup 1.0000x reference)
//
#include <hip/hip_runtime.h>
#include <cstddef>

static constexpr int NN = 100000;   // nodes
static constexpr int NE = 1600000;  // edges
static constexpr int NODE_SHIFT = 8;                       // 256 nodes per bucket
static constexpr int NB = (NN + 255) >> NODE_SHIFT;        // 391 buckets
static constexpr int CHUNK = 8192;                         // edges per binning block
static constexpr int NCH = (NE + CHUNK - 1) / CHUNK;       // 196 chunks

typedef _Float16 f16x8 __attribute__((ext_vector_type(8)));
typedef float f32x4  __attribute__((ext_vector_type(4)));

// accumulate 8 packed f16 (uint4) into a[0..8)
__device__ __forceinline__ void acc8h(const uint4& v, float* a) {
    union { uint4 u; _Float16 h[8]; } t; t.u = v;
#pragma unroll
    for (int j = 0; j < 8; j++) a[j] += (float)t.h[j];
}

// ---------------- bucketed CSR construction ----------------

__global__ void bucket_count(const int* __restrict__ eidx, int* __restrict__ bcnt) {
    __shared__ int h[NB];
    for (int i = threadIdx.x; i < NB; i += 256) h[i] = 0;
    __syncthreads();
    int base = blockIdx.x * CHUNK;
    int end = min(base + CHUNK, NE);
    for (int e = base + threadIdx.x; e < end; e += 256)
        atomicAdd(&h[eidx[NE + e] >> NODE_SHIFT], 1);
    __syncthreads();
    for (int i = threadIdx.x; i < NB; i += 256)
        if (h[i]) atomicAdd(&bcnt[i], h[i]);
}

__global__ void bucket_scan(const int* __restrict__ bcnt, int* __restrict__ bbase,
                            int* __restrict__ bcur, int* __restrict__ row_ptr) {
    __shared__ int s[512];
    int t = threadIdx.x;
    int v = (t < NB) ? bcnt[t] : 0;
    s[t] = v; __syncthreads();
    for (int off = 1; off < 512; off <<= 1) {
        int x = (t >= off) ? s[t - off] : 0;
        __syncthreads();
        s[t] += x;
        __syncthreads();
    }
    if (t < NB) { int e = s[t] - v; bbase[t] = e; bcur[t] = e; }
    if (t == 0) { bbase[NB] = NE; row_ptr[NN] = NE; }
}

__global__ void bucket_scatter(const int* __restrict__ eidx, int* __restrict__ bcur,
                               uint2* __restrict__ pairs) {
    __shared__ int h[NB];
    __shared__ int cur[NB];
    __shared__ int off[NB];
    for (int i = threadIdx.x; i < NB; i += 256) { h[i] = 0; cur[i] = 0; }
    __syncthreads();
    int base = blockIdx.x * CHUNK;
    int end = min(base + CHUNK, NE);
    for (int e = base + threadIdx.x; e < end; e += 256)
        atomicAdd(&h[eidx[NE + e] >> NODE_SHIFT], 1);
    __syncthreads();
    for (int i = threadIdx.x; i < NB; i += 256)
        off[i] = h[i] ? atomicAdd(&bcur[i], h[i]) : 0;
    __syncthreads();
    for (int e = base + threadIdx.x; e < end; e += 256) {
        int d = eidx[NE + e], s = eidx[e];
        int b = d >> NODE_SHIFT;
        int p = atomicAdd(&cur[b], 1);
        pairs[off[b] + p] = make_uint2((unsigned)s, (unsigned)d);
    }
}

__launch_bounds__(256)
__global__ void bucket_csr(const uint2* __restrict__ pairs, const int* __restrict__ bbase,
                           int* __restrict__ row_ptr, int* __restrict__ ecsr) {
    __shared__ int hist[256];
    __shared__ int scn[256];
    __shared__ int cur[256];
    int b = blockIdx.x, t = threadIdx.x;
    int ebeg = bbase[b], eend = bbase[b + 1];
    int node0 = b << NODE_SHIFT;
    hist[t] = 0;
    __syncthreads();
    for (int e = ebeg + t; e < eend; e += 256)
        atomicAdd(&hist[pairs[e].y & 255u], 1);
    __syncthreads();
    int v = hist[t];
    scn[t] = v; __syncthreads();
    for (int off = 1; off < 256; off <<= 1) {
        int x = (t >= off) ? scn[t - off] : 0;
        __syncthreads();
        scn[t] += x;
        __syncthreads();
    }
    int excl = scn[t] - v;
    int node = node0 + t;
    if (node < NN) row_ptr[node] = ebeg + excl;
    cur[t] = excl;
    __syncthreads();
    for (int e = ebeg + t; e < eend; e += 256) {
        uint2 pr = pairs[e];
        int p = atomicAdd(&cur[pr.y & 255u], 1);
        ecsr[ebeg + p] = (int)pr.x;
    }
}

// ---------------- fused conversions + bcnt zeroing (one launch) ----------------
// blocks [0,25000): x -> f16 bufP cols [64,128)
// blocks [25000,25288): the six W -> Wt^T f16 conversions
// blocks [25288,25290): zero bcnt
__global__ void conv_fused(const float* __restrict__ x,
                           const float* __restrict__ W1l, const float* __restrict__ W1r,
                           const float* __restrict__ Wlin1, const float* __restrict__ W2l,
                           const float* __restrict__ W2r, const float* __restrict__ Wlin2,
                           unsigned short* __restrict__ bufP, unsigned short* __restrict__ Wt1,
                           unsigned short* __restrict__ Wtl1, unsigned short* __restrict__ Wt2,
                           unsigned short* __restrict__ Wtf, int* __restrict__ bcnt) {
    int bid = blockIdx.x, t = threadIdx.x;
    union { _Float16 h; unsigned short u; } cv;
    if (bid < 25000) {
        int idx = bid * 256 + t;               // < NN*64 = 6.4M exactly
        int r = idx >> 6, c = idx & 63;
        cv.h = (_Float16)x[idx];
        bufP[(size_t)r * 128 + 64 + c] = cv.u;
    } else if (bid >= 25288) {
        int i = (bid - 25288) * 256 + t;
        if (i < NB) bcnt[i] = 0;
    } else {
        int b = bid - 25000;
        const float* W; unsigned short* Wt; int K, C, wld, kbase, base;
        if (b < 32)       { W = W1l;   Wt = Wt1;  K = 64;  C = 128; wld = 128; kbase = 0;   base = b; }
        else if (b < 64)  { W = W1r;   Wt = Wt1;  K = 64;  C = 128; wld = 128; kbase = 64;  base = b - 32; }
        else if (b < 128) { W = Wlin1; Wt = Wtl1; K = 128; C = 128; wld = 128; kbase = 0;   base = b - 64; }
        else if (b < 192) { W = W2l;   Wt = Wt2;  K = 128; C = 128; wld = 256; kbase = 0;   base = b - 128; }
        else if (b < 256) { W = W2r;   Wt = Wt2;  K = 128; C = 128; wld = 256; kbase = 128; base = b - 192; }
        else              { W = Wlin2; Wt = Wtf;  K = 128; C = 64;  wld = 128; kbase = 0;   base = b - 256; }
        int idx = base * 256 + t;
        if (idx < K * C) {
            int k = idx / C, c = idx % C;
            cv.h = (_Float16)W[idx];
            Wt[(size_t)c * wld + kbase + k] = cv.u;
        }
    }
}

// ---------------- mean aggregation (f16 gather, 16B/lane, x8 unroll) ----------------

// layer 1: gather f16 x rows (bufP cols [64,128), 128B), mean -> bufP cols [0,64)
__launch_bounds__(256)
__global__ void agg1(const unsigned short* __restrict__ xp, const int* __restrict__ row_ptr,
                     const int* __restrict__ ecsr, unsigned short* __restrict__ outp) {
    constexpr int TPN = 8;
    int node = blockIdx.x * (256 / TPN) + threadIdx.x / TPN;
    int lane = threadIdx.x % TPN;
    if (node >= NN) return;
    int beg = row_ptr[node], end = row_ptr[node + 1];

    float a0[8] = {0,0,0,0,0,0,0,0}, a1[8] = {0,0,0,0,0,0,0,0};
    float a2[8] = {0,0,0,0,0,0,0,0}, a3[8] = {0,0,0,0,0,0,0,0};
    int i = beg;
    for (; i + 8 <= end; i += 8) {
        int s0 = ecsr[i], s1 = ecsr[i+1], s2 = ecsr[i+2], s3 = ecsr[i+3];
        int s4 = ecsr[i+4], s5 = ecsr[i+5], s6 = ecsr[i+6], s7 = ecsr[i+7];
        uint4 v0 = *(const uint4*)&xp[(size_t)s0 * 128 + 64 + lane * 8];
        uint4 v1 = *(const uint4*)&xp[(size_t)s1 * 128 + 64 + lane * 8];
        uint4 v2 = *(const uint4*)&xp[(size_t)s2 * 128 + 64 + lane * 8];
        uint4 v3 = *(const uint4*)&xp[(size_t)s3 * 128 + 64 + lane * 8];
        uint4 v4 = *(const uint4*)&xp[(size_t)s4 * 128 + 64 + lane * 8];
        uint4 v5 = *(const uint4*)&xp[(size_t)s5 * 128 + 64 + lane * 8];
        uint4 v6 = *(const uint4*)&xp[(size_t)s6 * 128 + 64 + lane * 8];
        uint4 v7 = *(const uint4*)&xp[(size_t)s7 * 128 + 64 + lane * 8];
        acc8h(v0, a0); acc8h(v1, a1); acc8h(v2, a2); acc8h(v3, a3);
        acc8h(v4, a0); acc8h(v5, a1); acc8h(v6, a2); acc8h(v7, a3);
    }
    for (; i + 4 <= end; i += 4) {
        int s0 = ecsr[i], s1 = ecsr[i+1], s2 = ecsr[i+2], s3 = ecsr[i+3];
        uint4 v0 = *(const uint4*)&xp[(size_t)s0 * 128 + 64 + lane * 8];
        uint4 v1 = *(const uint4*)&xp[(size_t)s1 * 128 + 64 + lane * 8];
        uint4 v2 = *(const uint4*)&xp[(size_t)s2 * 128 + 64 + lane * 8];
        uint4 v3 = *(const uint4*)&xp[(size_t)s3 * 128 + 64 + lane * 8];
        acc8h(v0, a0); acc8h(v1, a1); acc8h(v2, a2); acc8h(v3, a3);
    }
    for (; i < end; i++) {
        uint4 v0 = *(const uint4*)&xp[(size_t)ecsr[i] * 128 + 64 + lane * 8];
        acc8h(v0, a0);
    }
    int deg = end - beg;
    float r = (deg > 0) ? 1.f / (float)deg : 0.f;
    union { uint4 u; _Float16 h[8]; } o;
#pragma unroll
    for (int j = 0; j < 8; j++)
        o.h[j] = (_Float16)((a0[j] + a1[j] + a2[j] + a3[j]) * r);
    *(uint4*)(outp + (size_t)node * 128 + lane * 8) = o.u;
}

// layer 2: gather f16 h rows (bufQ cols [128,256), 256B), mean -> bufQ cols [0,128)
__launch_bounds__(256)
__global__ void agg2(const unsigned short* __restrict__ hbuf, const int* __restrict__ row_ptr,
                     const int* __restrict__ ecsr, unsigned short* __restrict__ outp) {
    constexpr int TPN = 16;
    int node = blockIdx.x * (256 / TPN) + threadIdx.x / TPN;
    int lane = threadIdx.x % TPN;
    if (node >= NN) return;
    int beg = row_ptr[node], end = row_ptr[node + 1];

    float a0[8] = {0,0,0,0,0,0,0,0}, a1[8] = {0,0,0,0,0,0,0,0};
    float a2[8] = {0,0,0,0,0,0,0,0}, a3[8] = {0,0,0,0,0,0,0,0};
    int i = beg;
    for (; i + 8 <= end; i += 8) {
        int s0 = ecsr[i], s1 = ecsr[i+1], s2 = ecsr[i+2], s3 = ecsr[i+3];
        int s4 = ecsr[i+4], s5 = ecsr[i+5], s6 = ecsr[i+6], s7 = ecsr[i+7];
        uint4 v0 = *(const uint4*)&hbuf[(size_t)s0 * 256 + 128 + lane * 8];
        uint4 v1 = *(const uint4*)&hbuf[(size_t)s1 * 256 + 128 + lane * 8];
        uint4 v2 = *(const uint4*)&hbuf[(size_t)s2 * 256 + 128 + lane * 8];
        uint4 v3 = *(const uint4*)&hbuf[(size_t)s3 * 256 + 128 + lane * 8];
        uint4 v4 = *(const uint4*)&hbuf[(size_t)s4 * 256 + 128 + lane * 8];
        uint4 v5 = *(const uint4*)&hbuf[(size_t)s5 * 256 + 128 + lane * 8];
        uint4 v6 = *(const uint4*)&hbuf[(size_t)s6 * 256 + 128 + lane * 8];
        uint4 v7 = *(const uint4*)&hbuf[(size_t)s7 * 256 + 128 + lane * 8];
        acc8h(v0, a0); acc8h(v1, a1); acc8h(v2, a2); acc8h(v3, a3);
        acc8h(v4, a0); acc8h(v5, a1); acc8h(v6, a2); acc8h(v7, a3);
    }
    for (; i + 4 <= end; i += 4) {
        int s0 = ecsr[i], s1 = ecsr[i+1], s2 = ecsr[i+2], s3 = ecsr[i+3];
        uint4 v0 = *(const uint4*)&hbuf[(size_t)s0 * 256 + 128 + lane * 8];
        uint4 v1 = *(const uint4*)&hbuf[(size_t)s1 * 256 + 128 + lane * 8];
        uint4 v2 = *(const uint4*)&hbuf[(size_t)s2 * 256 + 128 + lane * 8];
        uint4 v3 = *(const uint4*)&hbuf[(size_t)s3 * 256 + 128 + lane * 8];
        acc8h(v0, a0); acc8h(v1, a1); acc8h(v2, a2); acc8h(v3, a3);
    }
    for (; i < end; i++) {
        uint4 v0 = *(const uint4*)&hbuf[(size_t)ecsr[i] * 256 + 128 + lane * 8];
        acc8h(v0, a0);
    }
    int deg = end - beg;
    float r = (deg > 0) ? 1.f / (float)deg : 0.f;
    union { uint4 u; _Float16 h[8]; } o;
#pragma unroll
    for (int j = 0; j < 8; j++)
        o.h[j] = (_Float16)((a0[j] + a1[j] + a2[j] + a3[j]) * r);
    *(uint4*)(outp + (size_t)node * 256 + lane * 8) = o.u;
}

// ---------------- single-pass f16 MFMA GEMM, register-prefetch pipelined ----------------
// out[M x C] = A[M x K] @ Wt^T + bias (Wt is [C x K] row-major), optional relu.
// Prefetch next K-chunk into VGPRs right after barrier 1 so global latency
// overlaps the MFMA block. __launch_bounds__(256,3): VGPR cap ~170 (est ~145,
// no spill); grid=782 caps at ~3 blocks/CU anyway.
template<int K, int C, bool RELU, bool F16OUT>
__launch_bounds__(256, 3)
__global__ void gemm_f16(const unsigned short* __restrict__ A, int lda,
                         const unsigned short* __restrict__ Wt,
                         const float* __restrict__ bias,
                         unsigned short* __restrict__ outp, int old_, int obase,
                         float* __restrict__ outf) {
    constexpr int BM  = 128;
    constexpr int NKC = K / 64;
    constexpr int RT  = (C == 128) ? 4 : 2;
    constexpr int NA  = BM * 8 / 256;   // uint4 staging slots per thread (A) = 4
    constexpr int NW  = C * 8 / 256;    // (W) = 4 or 2
    __shared__ unsigned short As[BM * 72];
    __shared__ unsigned short Ws[C * 72];

    const int tid  = threadIdx.x;
    const int lane = tid & 63, wave = tid >> 6;
    const int lrow = lane & 15, quad = lane >> 4;
    const int wrow0 = (C == 128) ? (wave >> 1) * 64 : wave * 32;
    const int wcol0 = (C == 128) ? (wave & 1) * 64 : 0;
    const int row0  = blockIdx.x * BM;

    uint4 pa[NA], pw[NW];
    auto loadA = [&](int it) {
#pragma unroll
        for (int j = 0; j < NA; j++) {
            int tt = tid + j * 256; int r = tt >> 3, c8 = (tt & 7) * 8;
            int gr = row0 + r;
            pa[j] = (gr < NN) ? *(const uint4*)&A[(size_t)gr * lda + it * 64 + c8]
                              : make_uint4(0u, 0u, 0u, 0u);
        }
    };
    auto loadW = [&](int it) {
#pragma unroll
        for (int j = 0; j < NW; j++) {
            int tt = tid + j * 256; int wr = tt >> 3, c8 = (tt & 7) * 8;
            pw[j] = *(const uint4*)&Wt[(size_t)wr * K + it * 64 + c8];
        }
    };

    f32x4 acc[RT][4];
#pragma unroll
    for (int a = 0; a < RT; a++)
#pragma unroll
        for (int b = 0; b < 4; b++) acc[a][b] = (f32x4){0.f, 0.f, 0.f, 0.f};

    loadA(0); loadW(0);
#pragma unroll 1
    for (int it = 0; it < NKC; ++it) {
#pragma unroll
        for (int j = 0; j < NA; j++) {
            int tt = tid + j * 256; int r = tt >> 3, c8 = (tt & 7) * 8;
            *(uint4*)&As[r * 72 + c8] = pa[j];
        }
#pragma unroll
        for (int j = 0; j < NW; j++) {
            int tt = tid + j * 256; int wr = tt >> 3, c8 = (tt & 7) * 8;
            *(uint4*)&Ws[wr * 72 + c8] = pw[j];
        }
        __syncthreads();
        if (it + 1 < NKC) { loadA(it + 1); loadW(it + 1); }
#pragma unroll
        for (int ks = 0; ks < 2; ++ks) {
            f16x8 af[RT], bfr[4];
#pragma unroll
            for (int rt = 0; rt < RT; rt++)
                af[rt] = *(const f16x8*)&As[(wrow0 + rt * 16 + lrow) * 72 + ks * 32 + quad * 8];
#pragma unroll
            for (int ct = 0; ct < 4; ct++)
                bfr[ct] = *(const f16x8*)&Ws[(wcol0 + ct * 16 + lrow) * 72 + ks * 32 + quad * 8];
#pragma unroll
            for (int rt = 0; rt < RT; rt++)
#pragma unroll
                for (int ct = 0; ct < 4; ct++)
                    acc[rt][ct] = __builtin_amdgcn_mfma_f32_16x16x32_f16(
                        af[rt], bfr[ct], acc[rt][ct], 0, 0, 0);
        }
        __syncthreads();
    }

    // epilogue: C/D layout col=lane&15, row=quad*4+reg [m89/m91 verified]
    float bcol[4];
#pragma unroll
    for (int ct = 0; ct < 4; ct++) bcol[ct] = bias[wcol0 + ct * 16 + lrow];
#pragma unroll
    for (int rt = 0; rt < RT; rt++) {
#pragma unroll
        for (int ct = 0; ct < 4; ct++) {
#pragma unroll
            for (int r = 0; r < 4; r++) {
                int grow = row0 + wrow0 + rt * 16 + quad * 4 + r;
                if (grow < NN) {
                    int col = wcol0 + ct * 16 + lrow;
                    float v = acc[rt][ct][r] + bcol[ct];
                    if (RELU) v = fmaxf(v, 0.f);
                    if (F16OUT) {
                        union { _Float16 h; unsigned short u; } cv;
                        cv.h = (_Float16)v;
                        outp[(size_t)grow * old_ + obase + col] = cv.u;
                    } else {
                        outf[(size_t)grow * C + col] = v;
                    }
                }
            }
        }
    }
}

// ---------------- launch ----------------

extern "C" void kernel_launch(void* const* d_in, const int* in_sizes, int n_in,
                              void* d_out, int out_size, void* d_ws, size_t ws_size,
                              hipStream_t stream) {
    const float* x     = (const float*)d_in[0];
    const int*   eidx  = (const int*)d_in[1];
    const float* W1l   = (const float*)d_in[2];
    const float* b1    = (const float*)d_in[3];
    const float* W1r   = (const float*)d_in[4];
    const float* Wlin1 = (const float*)d_in[5];
    const float* blin1 = (const float*)d_in[6];
    const float* W2l   = (const float*)d_in[7];
    const float* b2    = (const float*)d_in[8];
    const float* W2r   = (const float*)d_in[9];
    const float* Wlin2 = (const float*)d_in[10];
    const float* blin2 = (const float*)d_in[11];
    float* out = (float*)d_out;
    (void)in_sizes; (void)n_in; (void)out_size; (void)ws_size;

    char* ws = (char*)d_ws;
    size_t off = 0;
    auto alloc = [&](size_t bytes) -> void* {
        void* p = ws + off;
        off = (off + bytes + 255) & ~(size_t)255;
        return p;
    };
    int* bcnt    = (int*)alloc((size_t)NB * 4);
    int* bbase   = (int*)alloc((size_t)(NB + 1) * 4);
    int* bcur    = (int*)alloc((size_t)NB * 4);
    int* row_ptr = (int*)alloc((size_t)(NN + 1) * 4);
    int* ecsr    = (int*)alloc((size_t)NE * 4);
    uint2* pairs = (uint2*)alloc((size_t)NE * 8);
    unsigned short* Wt1  = (unsigned short*)alloc((size_t)128 * 128 * 2);  // [W1l|W1r]^T
    unsigned short* Wtl1 = (unsigned short*)alloc((size_t)128 * 128 * 2);  // Wlin1^T
    unsigned short* Wt2  = (unsigned short*)alloc((size_t)128 * 256 * 2);  // [W2l|W2r]^T
    unsigned short* Wtf  = (unsigned short*)alloc((size_t)64  * 128 * 2);  // Wlin2^T
    unsigned short* bufP = (unsigned short*)alloc((size_t)NN * 128 * 2);   // [mean1|x] f16
    unsigned short* bufQ = (unsigned short*)alloc((size_t)NN * 256 * 2);   // [mean2|h] f16
    unsigned short* bufR = (unsigned short*)alloc((size_t)NN * 128 * 2);   // h1 / h2 f16

    // fused conversions + bcnt zeroing (1 launch replaces 8)
    conv_fused<<<25290, 256, 0, stream>>>(x, W1l, W1r, Wlin1, W2l, W2r, Wlin2,
                                          bufP, Wt1, Wtl1, Wt2, Wtf, bcnt);

    // bucketed CSR build
    bucket_count<<<NCH, 256, 0, stream>>>(eidx, bcnt);
    bucket_scan<<<1, 512, 0, stream>>>(bcnt, bbase, bcur, row_ptr);
    bucket_scatter<<<NCH, 256, 0, stream>>>(eidx, bcur, pairs);
    bucket_csr<<<NB, 256, 0, stream>>>(pairs, bbase, row_ptr, ecsr);

    // mean1 -> bufP cols 0..63
    agg1<<<(NN + 31) / 32, 256, 0, stream>>>(bufP, row_ptr, ecsr, bufP);

    const int GB128 = (NN + 127) / 128;

    // L1 SAGE: bufP[mean1|x] @ [W1l;W1r] + b1, relu -> h1 (bufR)
    gemm_f16<128, 128, true, true><<<GB128, 256, 0, stream>>>(
        bufP, 128, Wt1, b1, bufR, 128, 0, nullptr);
    // lin1: h1 @ Wlin1 + blin1, relu -> h (bufQ cols 128..255)
    gemm_f16<128, 128, true, true><<<GB128, 256, 0, stream>>>(
        bufR, 128, Wtl1, blin1, bufQ, 256, 128, nullptr);
    // mean2 from h -> bufQ cols 0..127
    agg2<<<(NN + 15) / 16, 256, 0, stream>>>(bufQ, row_ptr, ecsr, bufQ);
    // L2 SAGE: bufQ[mean2|h] @ [W2l;W2r] + b2, relu -> h2 (bufR)
    gemm_f16<256, 128, true, true><<<GB128, 256, 0, stream>>>(
        bufQ, 256, Wt2, b2, bufR, 128, 0, nullptr);
    // final: h2 @ Wlin2 + blin2 -> fp32 out
    gemm_f16<128, 64, false, false><<<GB128, 256, 0, stream>>>(
        bufR, 128, Wtf, blin2, nullptr, 0, 0, out);
}

// Round 11
// 321.042 us; speedup vs baseline: 1.1260x; 1.1260x over previous
//
#include <hip/hip_runtime.h>
#include <cstddef>

static constexpr int NN = 100000;   // nodes
static constexpr int NE = 1600000;  // edges
static constexpr int NODE_SHIFT = 8;                       // 256 nodes per bucket
static constexpr int NB = (NN + 255) >> NODE_SHIFT;        // 391 buckets
static constexpr int CHUNK = 8192;                         // edges per binning block
static constexpr int NCH = (NE + CHUNK - 1) / CHUNK;       // 196 chunks

typedef _Float16 f16x8 __attribute__((ext_vector_type(8)));
typedef float f32x4  __attribute__((ext_vector_type(4)));

// accumulate 8 packed f16 (uint4) into a[0..8)
__device__ __forceinline__ void acc8h(const uint4& v, float* a) {
    union { uint4 u; _Float16 h[8]; } t; t.u = v;
#pragma unroll
    for (int j = 0; j < 8; j++) a[j] += (float)t.h[j];
}

// ---------------- bucketed CSR construction ----------------

__global__ void bucket_count(const int* __restrict__ eidx, int* __restrict__ bcnt) {
    __shared__ int h[NB];
    for (int i = threadIdx.x; i < NB; i += 256) h[i] = 0;
    __syncthreads();
    int base = blockIdx.x * CHUNK;
    int end = min(base + CHUNK, NE);
    for (int e = base + threadIdx.x; e < end; e += 256)
        atomicAdd(&h[eidx[NE + e] >> NODE_SHIFT], 1);
    __syncthreads();
    for (int i = threadIdx.x; i < NB; i += 256)
        if (h[i]) atomicAdd(&bcnt[i], h[i]);
}

__global__ void bucket_scan(const int* __restrict__ bcnt, int* __restrict__ bbase,
                            int* __restrict__ bcur, int* __restrict__ row_ptr) {
    __shared__ int s[512];
    int t = threadIdx.x;
    int v = (t < NB) ? bcnt[t] : 0;
    s[t] = v; __syncthreads();
    for (int off = 1; off < 512; off <<= 1) {
        int x = (t >= off) ? s[t - off] : 0;
        __syncthreads();
        s[t] += x;
        __syncthreads();
    }
    if (t < NB) { int e = s[t] - v; bbase[t] = e; bcur[t] = e; }
    if (t == 0) { bbase[NB] = NE; row_ptr[NN] = NE; }
}

__global__ void bucket_scatter(const int* __restrict__ eidx, int* __restrict__ bcur,
                               uint2* __restrict__ pairs) {
    __shared__ int h[NB];
    __shared__ int cur[NB];
    __shared__ int off[NB];
    for (int i = threadIdx.x; i < NB; i += 256) { h[i] = 0; cur[i] = 0; }
    __syncthreads();
    int base = blockIdx.x * CHUNK;
    int end = min(base + CHUNK, NE);
    for (int e = base + threadIdx.x; e < end; e += 256)
        atomicAdd(&h[eidx[NE + e] >> NODE_SHIFT], 1);
    __syncthreads();
    for (int i = threadIdx.x; i < NB; i += 256)
        off[i] = h[i] ? atomicAdd(&bcur[i], h[i]) : 0;
    __syncthreads();
    for (int e = base + threadIdx.x; e < end; e += 256) {
        int d = eidx[NE + e], s = eidx[e];
        int b = d >> NODE_SHIFT;
        int p = atomicAdd(&cur[b], 1);
        pairs[off[b] + p] = make_uint2((unsigned)s, (unsigned)d);
    }
}

__launch_bounds__(256)
__global__ void bucket_csr(const uint2* __restrict__ pairs, const int* __restrict__ bbase,
                           int* __restrict__ row_ptr, int* __restrict__ ecsr) {
    __shared__ int hist[256];
    __shared__ int scn[256];
    __shared__ int cur[256];
    int b = blockIdx.x, t = threadIdx.x;
    int ebeg = bbase[b], eend = bbase[b + 1];
    int node0 = b << NODE_SHIFT;
    hist[t] = 0;
    __syncthreads();
    for (int e = ebeg + t; e < eend; e += 256)
        atomicAdd(&hist[pairs[e].y & 255u], 1);
    __syncthreads();
    int v = hist[t];
    scn[t] = v; __syncthreads();
    for (int off = 1; off < 256; off <<= 1) {
        int x = (t >= off) ? scn[t - off] : 0;
        __syncthreads();
        scn[t] += x;
        __syncthreads();
    }
    int excl = scn[t] - v;
    int node = node0 + t;
    if (node < NN) row_ptr[node] = ebeg + excl;
    cur[t] = excl;
    __syncthreads();
    for (int e = ebeg + t; e < eend; e += 256) {
        uint2 pr = pairs[e];
        int p = atomicAdd(&cur[pr.y & 255u], 1);
        ecsr[ebeg + p] = (int)pr.x;
    }
}

// ---------------- fused conversions + bcnt zeroing (one launch) ----------------
// blocks [0,25000): x -> f16 bufP cols [64,128)
// blocks [25000,25288): the six W -> Wt^T f16 conversions
// blocks [25288,25290): zero bcnt
__global__ void conv_fused(const float* __restrict__ x,
                           const float* __restrict__ W1l, const float* __restrict__ W1r,
                           const float* __restrict__ Wlin1, const float* __restrict__ W2l,
                           const float* __restrict__ W2r, const float* __restrict__ Wlin2,
                           unsigned short* __restrict__ bufP, unsigned short* __restrict__ Wt1,
                           unsigned short* __restrict__ Wtl1, unsigned short* __restrict__ Wt2,
                           unsigned short* __restrict__ Wtf, int* __restrict__ bcnt) {
    int bid = blockIdx.x, t = threadIdx.x;
    union { _Float16 h; unsigned short u; } cv;
    if (bid < 25000) {
        int idx = bid * 256 + t;               // < NN*64 = 6.4M exactly
        int r = idx >> 6, c = idx & 63;
        cv.h = (_Float16)x[idx];
        bufP[(size_t)r * 128 + 64 + c] = cv.u;
    } else if (bid >= 25288) {
        int i = (bid - 25288) * 256 + t;
        if (i < NB) bcnt[i] = 0;
    } else {
        int b = bid - 25000;
        const float* W; unsigned short* Wt; int K, C, wld, kbase, base;
        if (b < 32)       { W = W1l;   Wt = Wt1;  K = 64;  C = 128; wld = 128; kbase = 0;   base = b; }
        else if (b < 64)  { W = W1r;   Wt = Wt1;  K = 64;  C = 128; wld = 128; kbase = 64;  base = b - 32; }
        else if (b < 128) { W = Wlin1; Wt = Wtl1; K = 128; C = 128; wld = 128; kbase = 0;   base = b - 64; }
        else if (b < 192) { W = W2l;   Wt = Wt2;  K = 128; C = 128; wld = 256; kbase = 0;   base = b - 128; }
        else if (b < 256) { W = W2r;   Wt = Wt2;  K = 128; C = 128; wld = 256; kbase = 128; base = b - 192; }
        else              { W = Wlin2; Wt = Wtf;  K = 128; C = 64;  wld = 128; kbase = 0;   base = b - 256; }
        int idx = base * 256 + t;
        if (idx < K * C) {
            int k = idx / C, c = idx % C;
            cv.h = (_Float16)W[idx];
            Wt[(size_t)c * wld + kbase + k] = cv.u;
        }
    }
}

// ---------------- mean aggregation (f16 gather, 16B/lane, x4 unroll) ----------------
// Round-10 post-mortem: x8 unroll raised VGPR 40->52, occupancy 52->35%, dur UP.
// Gather kernels live on wave-level parallelism; keep VGPR at 40 (x4 unroll).

// layer 1: gather f16 x rows (bufP cols [64,128), 128B), mean -> bufP cols [0,64)
__launch_bounds__(256)
__global__ void agg1(const unsigned short* __restrict__ xp, const int* __restrict__ row_ptr,
                     const int* __restrict__ ecsr, unsigned short* __restrict__ outp) {
    constexpr int TPN = 8;
    int node = blockIdx.x * (256 / TPN) + threadIdx.x / TPN;
    int lane = threadIdx.x % TPN;
    if (node >= NN) return;
    int beg = row_ptr[node], end = row_ptr[node + 1];

    float a0[8] = {0,0,0,0,0,0,0,0}, a1[8] = {0,0,0,0,0,0,0,0};
    float a2[8] = {0,0,0,0,0,0,0,0}, a3[8] = {0,0,0,0,0,0,0,0};
    int i = beg;
    for (; i + 4 <= end; i += 4) {
        int s0 = ecsr[i], s1 = ecsr[i + 1], s2 = ecsr[i + 2], s3 = ecsr[i + 3];
        uint4 v0 = *(const uint4*)&xp[(size_t)s0 * 128 + 64 + lane * 8];
        uint4 v1 = *(const uint4*)&xp[(size_t)s1 * 128 + 64 + lane * 8];
        uint4 v2 = *(const uint4*)&xp[(size_t)s2 * 128 + 64 + lane * 8];
        uint4 v3 = *(const uint4*)&xp[(size_t)s3 * 128 + 64 + lane * 8];
        acc8h(v0, a0); acc8h(v1, a1); acc8h(v2, a2); acc8h(v3, a3);
    }
    for (; i < end; i++) {
        uint4 v0 = *(const uint4*)&xp[(size_t)ecsr[i] * 128 + 64 + lane * 8];
        acc8h(v0, a0);
    }
    int deg = end - beg;
    float r = (deg > 0) ? 1.f / (float)deg : 0.f;
    union { uint4 u; _Float16 h[8]; } o;
#pragma unroll
    for (int j = 0; j < 8; j++)
        o.h[j] = (_Float16)((a0[j] + a1[j] + a2[j] + a3[j]) * r);
    *(uint4*)(outp + (size_t)node * 128 + lane * 8) = o.u;
}

// layer 2: gather f16 h rows (bufQ cols [128,256), 256B), mean -> bufQ cols [0,128)
__launch_bounds__(256)
__global__ void agg2(const unsigned short* __restrict__ hbuf, const int* __restrict__ row_ptr,
                     const int* __restrict__ ecsr, unsigned short* __restrict__ outp) {
    constexpr int TPN = 16;
    int node = blockIdx.x * (256 / TPN) + threadIdx.x / TPN;
    int lane = threadIdx.x % TPN;
    if (node >= NN) return;
    int beg = row_ptr[node], end = row_ptr[node + 1];

    float a0[8] = {0,0,0,0,0,0,0,0}, a1[8] = {0,0,0,0,0,0,0,0};
    float a2[8] = {0,0,0,0,0,0,0,0}, a3[8] = {0,0,0,0,0,0,0,0};
    int i = beg;
    for (; i + 4 <= end; i += 4) {
        int s0 = ecsr[i], s1 = ecsr[i + 1], s2 = ecsr[i + 2], s3 = ecsr[i + 3];
        uint4 v0 = *(const uint4*)&hbuf[(size_t)s0 * 256 + 128 + lane * 8];
        uint4 v1 = *(const uint4*)&hbuf[(size_t)s1 * 256 + 128 + lane * 8];
        uint4 v2 = *(const uint4*)&hbuf[(size_t)s2 * 256 + 128 + lane * 8];
        uint4 v3 = *(const uint4*)&hbuf[(size_t)s3 * 256 + 128 + lane * 8];
        acc8h(v0, a0); acc8h(v1, a1); acc8h(v2, a2); acc8h(v3, a3);
    }
    for (; i < end; i++) {
        uint4 v0 = *(const uint4*)&hbuf[(size_t)ecsr[i] * 256 + 128 + lane * 8];
        acc8h(v0, a0);
    }
    int deg = end - beg;
    float r = (deg > 0) ? 1.f / (float)deg : 0.f;
    union { uint4 u; _Float16 h[8]; } o;
#pragma unroll
    for (int j = 0; j < 8; j++)
        o.h[j] = (_Float16)((a0[j] + a1[j] + a2[j] + a3[j]) * r);
    *(uint4*)(outp + (size_t)node * 256 + lane * 8) = o.u;
}

// ---------------- single-pass f16 MFMA GEMM (round-9 structure) ----------------
// Round-10 post-mortem: register prefetch + (256,3) regressed (VGPR pressure,
// barrier drain structural — m97 lesson). Keep the simple 2-barrier loop, (256,4).
template<int K, int C, bool RELU, bool F16OUT>
__launch_bounds__(256, 4)
__global__ void gemm_f16(const unsigned short* __restrict__ A, int lda,
                         const unsigned short* __restrict__ Wt,
                         const float* __restrict__ bias,
                         unsigned short* __restrict__ outp, int old_, int obase,
                         float* __restrict__ outf) {
    constexpr int BM  = 128;
    constexpr int NKC = K / 64;
    constexpr int RT  = (C == 128) ? 4 : 2;
    __shared__ unsigned short As[BM * 72];
    __shared__ unsigned short Ws[C * 72];

    const int tid  = threadIdx.x;
    const int lane = tid & 63, wave = tid >> 6;
    const int lrow = lane & 15, quad = lane >> 4;
    const int wrow0 = (C == 128) ? (wave >> 1) * 64 : wave * 32;
    const int wcol0 = (C == 128) ? (wave & 1) * 64 : 0;
    const int row0  = blockIdx.x * BM;

    f32x4 acc[RT][4];
#pragma unroll
    for (int a = 0; a < RT; a++)
#pragma unroll
        for (int b = 0; b < 4; b++) acc[a][b] = (f32x4){0.f, 0.f, 0.f, 0.f};

#pragma unroll 1
    for (int it = 0; it < NKC; ++it) {
        int base = it * 64;
        for (int t = tid; t < BM * 8; t += 256) {
            int r = t >> 3, c8 = (t & 7) * 8;
            int gr = row0 + r;
            uint4 v = make_uint4(0u, 0u, 0u, 0u);
            if (gr < NN) v = *(const uint4*)&A[(size_t)gr * lda + base + c8];
            *(uint4*)&As[r * 72 + c8] = v;
        }
        for (int t = tid; t < C * 8; t += 256) {
            int wr = t >> 3, c8 = (t & 7) * 8;
            *(uint4*)&Ws[wr * 72 + c8] = *(const uint4*)&Wt[(size_t)wr * K + base + c8];
        }
        __syncthreads();
#pragma unroll
        for (int ks = 0; ks < 2; ++ks) {
            f16x8 af[RT], bfr[4];
#pragma unroll
            for (int rt = 0; rt < RT; rt++)
                af[rt] = *(const f16x8*)&As[(wrow0 + rt * 16 + lrow) * 72 + ks * 32 + quad * 8];
#pragma unroll
            for (int ct = 0; ct < 4; ct++)
                bfr[ct] = *(const f16x8*)&Ws[(wcol0 + ct * 16 + lrow) * 72 + ks * 32 + quad * 8];
#pragma unroll
            for (int rt = 0; rt < RT; rt++)
#pragma unroll
                for (int ct = 0; ct < 4; ct++)
                    acc[rt][ct] = __builtin_amdgcn_mfma_f32_16x16x32_f16(
                        af[rt], bfr[ct], acc[rt][ct], 0, 0, 0);
        }
        __syncthreads();
    }

    // epilogue: C/D layout col=lane&15, row=quad*4+reg [m89/m91 verified]
    float bcol[4];
#pragma unroll
    for (int ct = 0; ct < 4; ct++) bcol[ct] = bias[wcol0 + ct * 16 + lrow];
#pragma unroll
    for (int rt = 0; rt < RT; rt++) {
#pragma unroll
        for (int ct = 0; ct < 4; ct++) {
#pragma unroll
            for (int r = 0; r < 4; r++) {
                int grow = row0 + wrow0 + rt * 16 + quad * 4 + r;
                if (grow < NN) {
                    int col = wcol0 + ct * 16 + lrow;
                    float v = acc[rt][ct][r] + bcol[ct];
                    if (RELU) v = fmaxf(v, 0.f);
                    if (F16OUT) {
                        union { _Float16 h; unsigned short u; } cv;
                        cv.h = (_Float16)v;
                        outp[(size_t)grow * old_ + obase + col] = cv.u;
                    } else {
                        outf[(size_t)grow * C + col] = v;
                    }
                }
            }
        }
    }
}

// ---------------- launch ----------------

extern "C" void kernel_launch(void* const* d_in, const int* in_sizes, int n_in,
                              void* d_out, int out_size, void* d_ws, size_t ws_size,
                              hipStream_t stream) {
    const float* x     = (const float*)d_in[0];
    const int*   eidx  = (const int*)d_in[1];
    const float* W1l   = (const float*)d_in[2];
    const float* b1    = (const float*)d_in[3];
    const float* W1r   = (const float*)d_in[4];
    const float* Wlin1 = (const float*)d_in[5];
    const float* blin1 = (const float*)d_in[6];
    const float* W2l   = (const float*)d_in[7];
    const float* b2    = (const float*)d_in[8];
    const float* W2r   = (const float*)d_in[9];
    const float* Wlin2 = (const float*)d_in[10];
    const float* blin2 = (const float*)d_in[11];
    float* out = (float*)d_out;
    (void)in_sizes; (void)n_in; (void)out_size; (void)ws_size;

    char* ws = (char*)d_ws;
    size_t off = 0;
    auto alloc = [&](size_t bytes) -> void* {
        void* p = ws + off;
        off = (off + bytes + 255) & ~(size_t)255;
        return p;
    };
    int* bcnt    = (int*)alloc((size_t)NB * 4);
    int* bbase   = (int*)alloc((size_t)(NB + 1) * 4);
    int* bcur    = (int*)alloc((size_t)NB * 4);
    int* row_ptr = (int*)alloc((size_t)(NN + 1) * 4);
    int* ecsr    = (int*)alloc((size_t)NE * 4);
    uint2* pairs = (uint2*)alloc((size_t)NE * 8);
    unsigned short* Wt1  = (unsigned short*)alloc((size_t)128 * 128 * 2);  // [W1l|W1r]^T
    unsigned short* Wtl1 = (unsigned short*)alloc((size_t)128 * 128 * 2);  // Wlin1^T
    unsigned short* Wt2  = (unsigned short*)alloc((size_t)128 * 256 * 2);  // [W2l|W2r]^T
    unsigned short* Wtf  = (unsigned short*)alloc((size_t)64  * 128 * 2);  // Wlin2^T
    unsigned short* bufP = (unsigned short*)alloc((size_t)NN * 128 * 2);   // [mean1|x] f16
    unsigned short* bufQ = (unsigned short*)alloc((size_t)NN * 256 * 2);   // [mean2|h] f16
    unsigned short* bufR = (unsigned short*)alloc((size_t)NN * 128 * 2);   // h1 / h2 f16

    // fused conversions + bcnt zeroing (1 launch replaces 8)
    conv_fused<<<25290, 256, 0, stream>>>(x, W1l, W1r, Wlin1, W2l, W2r, Wlin2,
                                          bufP, Wt1, Wtl1, Wt2, Wtf, bcnt);

    // bucketed CSR build
    bucket_count<<<NCH, 256, 0, stream>>>(eidx, bcnt);
    bucket_scan<<<1, 512, 0, stream>>>(bcnt, bbase, bcur, row_ptr);
    bucket_scatter<<<NCH, 256, 0, stream>>>(eidx, bcur, pairs);
    bucket_csr<<<NB, 256, 0, stream>>>(pairs, bbase, row_ptr, ecsr);

    // mean1 -> bufP cols 0..63
    agg1<<<(NN + 31) / 32, 256, 0, stream>>>(bufP, row_ptr, ecsr, bufP);

    const int GB128 = (NN + 127) / 128;

    // L1 SAGE: bufP[mean1|x] @ [W1l;W1r] + b1, relu -> h1 (bufR)
    gemm_f16<128, 128, true, true><<<GB128, 256, 0, stream>>>(
        bufP, 128, Wt1, b1, bufR, 128, 0, nullptr);
    // lin1: h1 @ Wlin1 + blin1, relu -> h (bufQ cols 128..255)
    gemm_f16<128, 128, true, true><<<GB128, 256, 0, stream>>>(
        bufR, 128, Wtl1, blin1, bufQ, 256, 128, nullptr);
    // mean2 from h -> bufQ cols 0..127
    agg2<<<(NN + 15) / 16, 256, 0, stream>>>(bufQ, row_ptr, ecsr, bufQ);
    // L2 SAGE: bufQ[mean2|h] @ [W2l;W2r] + b2, relu -> h2 (bufR)
    gemm_f16<256, 128, true, true><<<GB128, 256, 0, stream>>>(
        bufQ, 256, Wt2, b2, bufR, 128, 0, nullptr);
    // final: h2 @ Wlin2 + blin2 -> fp32 out
    gemm_f16<128, 64, false, false><<<GB128, 256, 0, stream>>>(
        bufR, 128, Wtf, blin2, nullptr, 0, 0, out);
}